// Round 16
// baseline (927.024 us; speedup 1.0000x reference)
//
#include <hip/hip_runtime.h>
#include <hip/hip_bf16.h>

typedef unsigned short u16;
typedef unsigned int   u32;
typedef short bf16x8 __attribute__((ext_vector_type(8)));
typedef float f32x4  __attribute__((ext_vector_type(4)));
typedef int   i32x2  __attribute__((ext_vector_type(2)));

#define NN 100000
#define EE 800000
#define NTILE 6250            // NN/16
#define NTB   1563            // ceil(NTILE/4)
#define EBLK  1536            // persistent edge blocks = 6 blocks/CU x 256 CU
#define TOTW  (EBLK * 4)      // persistent edge waves
#define SCB   98              // scan blocks (98*1024 >= NN)
#define GMAX  (NN + EE / 8 + 2)

#define MFMA16(a,b,c) __builtin_amdgcn_mfma_f32_16x16x32_bf16(a,b,c,0,0,0)

__device__ __forceinline__ float b2f(u16 u) {
    u32 x = ((u32)u) << 16;
    return __uint_as_float(x);
}
__device__ __forceinline__ u16 f2b(float f) {
    __hip_bfloat16 h = __float2bfloat16(f);
    return *reinterpret_cast<u16*>(&h);
}
__device__ __forceinline__ void splt(float v, u16& hi, u16& lo) {
    hi = f2b(v);
    lo = f2b(v - b2f(hi));
}

// ---------------- degree + group-table build ----------------
__global__ __launch_bounds__(256) void k_deg(const int* __restrict__ dst,
                                             int* __restrict__ deg) {
    int e = blockIdx.x * 256 + threadIdx.x;
    if (e < EE) atomicAdd(&deg[dst[e]], 1);
}

__global__ __launch_bounds__(1024) void k_scanA(const int* __restrict__ deg,
                                                int* __restrict__ part) {
    __shared__ int s[1024];
    int i = blockIdx.x * 1024 + threadIdx.x;
    int v = (i < NN) ? deg[i] : 0;
    s[threadIdx.x] = v;
    __syncthreads();
    for (int off = 512; off > 0; off >>= 1) {
        if ((int)threadIdx.x < off) s[threadIdx.x] += s[threadIdx.x + off];
        __syncthreads();
    }
    if (threadIdx.x == 0) part[blockIdx.x] = s[0];
}

__global__ void k_scanB(int* __restrict__ part) {
    if (threadIdx.x == 0 && blockIdx.x == 0) {
        int run = 0;
        for (int b = 0; b < SCB; ++b) { int v = part[b]; part[b] = run; run += v; }
        part[SCB] = run;
    }
}

__global__ __launch_bounds__(1024) void k_scanC(const int* __restrict__ deg,
                                                const int* __restrict__ part,
                                                int* __restrict__ rowptr) {
    __shared__ int s[1024];
    int i = blockIdx.x * 1024 + threadIdx.x;
    int v = (i < NN) ? deg[i] : 0;
    s[threadIdx.x] = v;
    __syncthreads();
    for (int off = 1; off < 1024; off <<= 1) {
        int t = ((int)threadIdx.x >= off) ? s[threadIdx.x - off] : 0;
        __syncthreads();
        s[threadIdx.x] += t;
        __syncthreads();
    }
    int incl = s[threadIdx.x];
    if (i < NN) rowptr[i] = part[blockIdx.x] + incl - v;
    if (i == NN - 1) rowptr[NN] = part[SCB];
}

__global__ __launch_bounds__(256) void k_ngrp(const int* __restrict__ deg,
                                              int* __restrict__ ngrp) {
    int i = blockIdx.x * 256 + threadIdx.x;
    if (i < NN) ngrp[i] = (deg[i] + 7) >> 3;
}

__global__ __launch_bounds__(256) void k_curinit(const int* __restrict__ grp_ptr,
                                                 int* __restrict__ cursor) {
    int i = blockIdx.x * 256 + threadIdx.x;
    if (i < NN) cursor[i] = grp_ptr[i] * 8;
}

// scatter edges into group-major interleaved slots: srcd2[slot] = {src, bits(d2)}
__global__ __launch_bounds__(256) void k_scatter(const int* __restrict__ src,
                                                 const int* __restrict__ dst,
                                                 const float* __restrict__ pos,
                                                 int* __restrict__ cursor,
                                                 int* __restrict__ srcd2) {
    int e = blockIdx.x * 256 + threadIdx.x;
    if (e >= EE) return;
    int d = dst[e], s = src[e];
    int p = atomicAdd(&cursor[d], 1);
    float dx = pos[s * 3 + 0] - pos[d * 3 + 0];
    float dy = pos[s * 3 + 1] - pos[d * 3 + 1];
    float dz = pos[s * 3 + 2] - pos[d * 3 + 2];
    float d2 = dx * dx + dy * dy + dz * dz;
    i32x2 st = {s, __float_as_int(d2)};
    *(i32x2*)(srcd2 + 2L * p) = st;
}

// packed group table: gtab[g] = (node<<4) | cnt  (cnt in 1..8); pad entry at [G]
__global__ __launch_bounds__(256) void k_gtab(const int* __restrict__ deg,
                                              const int* __restrict__ grp_ptr,
                                              int* __restrict__ gtab) {
    int n = blockIdx.x * 256 + threadIdx.x;
    if (n >= NN) return;
    if (n == 0) gtab[grp_ptr[NN]] = 0;
    int d = deg[n];
    int ng = (d + 7) >> 3;
    int base = grp_ptr[n];
    for (int k = 0; k < ng; ++k) {
        int cc = d - 8 * k; if (cc > 8) cc = 8;
        gtab[base + k] = (n << 4) | cc;
    }
}

// ---------------- weight swizzle (fp32 -> bf16 hi/lo B-frags) ----------------
__global__ __launch_bounds__(256) void k_swz(const float* t1W1, const float* t1W2, const float* t1W3,
                                             const float* t2W1, const float* t2W2, const float* t2W3,
                                             const float* t1Win, const float* t2Win,
                                             u16* __restrict__ WsA, u16* __restrict__ WsB) {
    int gid = blockIdx.x * 256 + threadIdx.x;   // 172032 exactly
    if (gid < 163840) {
        int L = gid / 20480;
        int r = gid % 20480;
        const float* W1 = (L < 4 ? t1W1 : t2W1) + (size_t)(L & 3) * 129 * 64;
        const float* W2 = (L < 4 ? t1W2 : t2W2) + (size_t)(L & 3) * 64 * 64;
        const float* W3 = (L < 4 ? t1W3 : t2W3) + (size_t)(L & 3) * 128 * 64;
        float w;
        int rr, f, e, lane, j, row, col;
        if (r < 8192) { rr = r; f = rr >> 9; e = rr & 511; lane = e >> 3; j = e & 7;
            row = (f >> 2) * 32 + (lane >> 4) * 8 + j; col = (f & 3) * 16 + (lane & 15);
            w = W1[row * 64 + col];
        } else if (r < 12288) { rr = r - 8192; f = rr >> 9; e = rr & 511; lane = e >> 3; j = e & 7;
            row = (f >> 2) * 32 + (lane >> 4) * 8 + j; col = (f & 3) * 16 + (lane & 15);
            w = W2[row * 64 + col];
        } else { rr = r - 12288; f = rr >> 9; e = rr & 511; lane = e >> 3; j = e & 7;
            row = (f >> 2) * 32 + (lane >> 4) * 8 + j; col = (f & 3) * 16 + (lane & 15);
            w = W3[row * 64 + col];
        }
        u16 hi, lo; splt(w, hi, lo);
        WsA[(size_t)L * 40960 + r] = hi;
        WsA[(size_t)L * 40960 + 20480 + r] = lo;
    } else {
        int t = gid - 163840;
        int sel = (t < 4096) ? 0 : 1;
        int rr = t & 4095;
        const float* Win = sel ? t2Win : t1Win;
        int f = rr >> 9, e = rr & 511, lane = e >> 3, j = e & 7;
        int row = (f >> 2) * 32 + (lane >> 4) * 8 + j;
        int col = (f & 3) * 16 + (lane & 15);
        float w = Win[row * 64 + col];
        u16 hi, lo; splt(w, hi, lo);
        WsB[sel * 8192 + rr] = hi;
        WsB[sel * 8192 + 4096 + rr] = lo;
    }
}

// ---------------- t1 proj fused with embed + layer-0 dst-half ----------------
__global__ __launch_bounds__(256) void k_proj1(const float* __restrict__ pos,
                                               const int* __restrict__ z,
                                               const float* __restrict__ emb,
                                               const u16* __restrict__ WinS,
                                               const u16* __restrict__ Wsl0,
                                               const float* __restrict__ b1,
                                               u16* __restrict__ hbx,
                                               float* __restrict__ accbT) {
    __shared__ u16 th[4][16 * 72];
    __shared__ u16 tl[4][16 * 72];
    int w = threadIdx.x >> 6;
    int tile = blockIdx.x * 4 + w;
    if (tile >= NTILE) return;
    int lane = threadIdx.x & 63, c = lane & 15, g = lane >> 4;
    int n0 = tile * 16, nr = n0 + c;
    u16* lh = th[w];
    u16* ll = tl[w];
    int zr = z[nr];
    const float* er = emb + (long)zr * 61 - 3;
    bf16x8 A0h, A0l, A1h, A1l;
#pragma unroll
    for (int j = 0; j < 8; ++j) {
        int f = 8 * g + j;
        float v1 = (f < 3) ? pos[nr * 3 + (f < 3 ? f : 0)] : er[f];
        float v2 = er[32 + 8 * g + j];
        u16 hi, lo;
        splt(v1, hi, lo); A0h[j] = (short)hi; A0l[j] = (short)lo;
        splt(v2, hi, lo); A1h[j] = (short)hi; A1l[j] = (short)lo;
    }
    const bf16x8* Wh = (const bf16x8*)WinS;
    const bf16x8* Wl = (const bf16x8*)(WinS + 4096);
#pragma unroll
    for (int nt = 0; nt < 4; ++nt) {
        f32x4 acc = {0.f, 0.f, 0.f, 0.f};
        acc = MFMA16(A0h, Wh[nt * 64 + lane], acc);
        acc = MFMA16(A1h, Wh[(4 + nt) * 64 + lane], acc);
        acc = MFMA16(A0l, Wh[nt * 64 + lane], acc);
        acc = MFMA16(A1l, Wh[(4 + nt) * 64 + lane], acc);
        acc = MFMA16(A0h, Wl[nt * 64 + lane], acc);
        acc = MFMA16(A1h, Wl[(4 + nt) * 64 + lane], acc);
#pragma unroll
        for (int r = 0; r < 4; ++r) {
            long n = n0 + 4 * g + r;
            u16 hi, lo; splt(acc[r], hi, lo);
            hbx[n * 128 + nt * 16 + c] = hi;
            hbx[n * 128 + 64 + nt * 16 + c] = lo;
            lh[(4 * g + r) * 72 + nt * 16 + c] = hi;
            ll[(4 * g + r) * 72 + nt * 16 + c] = lo;
        }
    }
    // layer-0 dst-half from LDS transpose (wave-private plane, no barrier)
    bf16x8 N0h = *(const bf16x8*)(lh + c * 72 + g * 8);
    bf16x8 N1h = *(const bf16x8*)(lh + c * 72 + 32 + g * 8);
    bf16x8 N0l = *(const bf16x8*)(ll + c * 72 + g * 8);
    bf16x8 N1l = *(const bf16x8*)(ll + c * 72 + 32 + g * 8);
    const bf16x8* W1h = (const bf16x8*)Wsl0;
    const bf16x8* W1l = (const bf16x8*)(Wsl0 + 20480);
    f32x4 acc4[4];
#pragma unroll
    for (int nt = 0; nt < 4; ++nt) {
        float bv = b1[nt * 16 + c];
        f32x4 a = {bv, bv, bv, bv};
        a = MFMA16(N0h, W1h[(8 + nt) * 64 + lane], a);
        a = MFMA16(N1h, W1h[(12 + nt) * 64 + lane], a);
        a = MFMA16(N0l, W1h[(8 + nt) * 64 + lane], a);
        a = MFMA16(N1l, W1h[(12 + nt) * 64 + lane], a);
        a = MFMA16(N0h, W1l[(8 + nt) * 64 + lane], a);
        a = MFMA16(N1h, W1l[(12 + nt) * 64 + lane], a);
        acc4[nt] = a;
    }
#pragma unroll
    for (int r = 0; r < 4; ++r) {
        f32x4 wv = {acc4[0][r], acc4[1][r], acc4[2][r], acc4[3][r]};
        *(f32x4*)(accbT + (long)(n0 + 4 * g + r) * 64 + c * 4) = wv;
    }
}

// ---------------- t2 proj fused with relu + layer-0 dst-half (in-place hbx) --
__global__ __launch_bounds__(256) void k_proj2(const u16* __restrict__ WinS,
                                               const u16* __restrict__ Wsl0,
                                               const float* __restrict__ b1,
                                               u16* __restrict__ hbx,
                                               float* __restrict__ accbT) {
    __shared__ u16 th[4][16 * 72];
    __shared__ u16 tl[4][16 * 72];
    int w = threadIdx.x >> 6;
    int tile = blockIdx.x * 4 + w;
    if (tile >= NTILE) return;
    int lane = threadIdx.x & 63, c = lane & 15, g = lane >> 4;
    int n0 = tile * 16, nr = n0 + c;
    u16* lh = th[w];
    u16* ll = tl[w];
    const bf16x8* p = (const bf16x8*)(hbx + (long)nr * 128);
    bf16x8 h0 = p[g], h1 = p[g + 4], l0 = p[g + 8], l1 = p[g + 12];
    bf16x8 A0h, A0l, A1h, A1l;
#pragma unroll
    for (int j = 0; j < 8; ++j) {
        float v1 = fmaxf(b2f((u16)h0[j]) + b2f((u16)l0[j]), 0.f);
        float v2 = fmaxf(b2f((u16)h1[j]) + b2f((u16)l1[j]), 0.f);
        u16 hi, lo;
        splt(v1, hi, lo); A0h[j] = (short)hi; A0l[j] = (short)lo;
        splt(v2, hi, lo); A1h[j] = (short)hi; A1l[j] = (short)lo;
    }
    const bf16x8* Wh = (const bf16x8*)WinS;
    const bf16x8* Wl = (const bf16x8*)(WinS + 4096);
#pragma unroll
    for (int nt = 0; nt < 4; ++nt) {
        f32x4 acc = {0.f, 0.f, 0.f, 0.f};
        acc = MFMA16(A0h, Wh[nt * 64 + lane], acc);
        acc = MFMA16(A1h, Wh[(4 + nt) * 64 + lane], acc);
        acc = MFMA16(A0l, Wh[nt * 64 + lane], acc);
        acc = MFMA16(A1l, Wh[(4 + nt) * 64 + lane], acc);
        acc = MFMA16(A0h, Wl[nt * 64 + lane], acc);
        acc = MFMA16(A1h, Wl[(4 + nt) * 64 + lane], acc);
#pragma unroll
        for (int r = 0; r < 4; ++r) {
            long n = n0 + 4 * g + r;
            u16 hi, lo; splt(acc[r], hi, lo);
            hbx[n * 128 + nt * 16 + c] = hi;
            hbx[n * 128 + 64 + nt * 16 + c] = lo;
            lh[(4 * g + r) * 72 + nt * 16 + c] = hi;
            ll[(4 * g + r) * 72 + nt * 16 + c] = lo;
        }
    }
    bf16x8 N0h = *(const bf16x8*)(lh + c * 72 + g * 8);
    bf16x8 N1h = *(const bf16x8*)(lh + c * 72 + 32 + g * 8);
    bf16x8 N0l = *(const bf16x8*)(ll + c * 72 + g * 8);
    bf16x8 N1l = *(const bf16x8*)(ll + c * 72 + 32 + g * 8);
    const bf16x8* W1h = (const bf16x8*)Wsl0;
    const bf16x8* W1l = (const bf16x8*)(Wsl0 + 20480);
    f32x4 acc4[4];
#pragma unroll
    for (int nt = 0; nt < 4; ++nt) {
        float bv = b1[nt * 16 + c];
        f32x4 a = {bv, bv, bv, bv};
        a = MFMA16(N0h, W1h[(8 + nt) * 64 + lane], a);
        a = MFMA16(N1h, W1h[(12 + nt) * 64 + lane], a);
        a = MFMA16(N0l, W1h[(8 + nt) * 64 + lane], a);
        a = MFMA16(N1l, W1h[(12 + nt) * 64 + lane], a);
        a = MFMA16(N0h, W1l[(8 + nt) * 64 + lane], a);
        a = MFMA16(N1h, W1l[(12 + nt) * 64 + lane], a);
        acc4[nt] = a;
    }
#pragma unroll
    for (int r = 0; r < 4; ++r) {
        f32x4 wv = {acc4[0][r], acc4[1][r], acc4[2][r], acc4[3][r]};
        *(f32x4*)(accbT + (long)(n0 + 4 * g + r) * 64 + c * 4) = wv;
    }
}

// ---------------- edge kernel: two 8-edge groups per MFMA tile ---------------
// interleaved srcd2 + packed gtab; partial sums -> sgrp[G,64] fp32
__global__ __launch_bounds__(256) void k_edges_mfma(const u16* __restrict__ hbx,
                                                    float* __restrict__ sgrp,
                                                    const int* __restrict__ srcd2,
                                                    const int* __restrict__ gtab,
                                                    const int* __restrict__ grp_ptr,
                                                    const u16* __restrict__ Wsl,
                                                    const float* __restrict__ W1f,
                                                    const float* __restrict__ accbT) {
    int lane = threadIdx.x & 63;
    int wid = blockIdx.x * 4 + (threadIdx.x >> 6);
    int c = lane & 15, g = lane >> 4;
    const bf16x8* W1H = (const bf16x8*)Wsl;
    const bf16x8* W1L = (const bf16x8*)(Wsl + 20480);
    bf16x8 w1h[2][4], w1l[2][4];
#pragma unroll
    for (int ks = 0; ks < 2; ++ks)
#pragma unroll
        for (int nt = 0; nt < 4; ++nt) {
            w1h[ks][nt] = W1H[(ks * 4 + nt) * 64 + lane];
            w1l[ks][nt] = W1L[(ks * 4 + nt) * 64 + lane];
        }
    float wdc[4];
#pragma unroll
    for (int nt = 0; nt < 4; ++nt) wdc[nt] = W1f[128 * 64 + nt * 16 + c];

    int G = grp_ptr[NN];
    int T = (G + 1) >> 1;
    int ro = 4 * (g & 1);

    for (int ti = wid; ti < T; ti += TOTW) {
        i32x2 pk = *(const i32x2*)(gtab + 2 * ti);
        int psel = (g < 2) ? pk[0] : pk[1];
        int nsel = psel >> 4;
        int csel = psel & 15;

        f32x4 bse = *(const f32x4*)(accbT + (long)nsel * 64 + c * 4);
        i32x2 ed = *(const i32x2*)(srcd2 + 2L * ((long)ti * 16 + c));
        int s = ed[0];
        float d2my = __int_as_float(ed[1]);
        const bf16x8* sp = (const bf16x8*)(hbx + (long)s * 128);
        bf16x8 A0h = sp[g], A1h = sp[g + 4], A0l = sp[g + 8], A1l = sp[g + 12];
        // dq[r] = d2 of tile-edge (4*g + r), held by lane (4*g + r)
        float dq[4];
#pragma unroll
        for (int r = 0; r < 4; ++r) dq[r] = __shfl(d2my, 4 * g + r, 64);

        float sv[4];
#pragma unroll
        for (int nt = 0; nt < 4; ++nt) {
            f32x4 ci;
#pragma unroll
            for (int r = 0; r < 4; ++r) ci[r] = bse[nt] + dq[r] * wdc[nt];
            ci = MFMA16(A0h, w1h[0][nt], ci);
            ci = MFMA16(A1h, w1h[1][nt], ci);
            ci = MFMA16(A0l, w1h[0][nt], ci);
            ci = MFMA16(A1l, w1h[1][nt], ci);
            ci = MFMA16(A0h, w1l[0][nt], ci);
            ci = MFMA16(A1h, w1l[1][nt], ci);
            float s4 = 0.f;
#pragma unroll
            for (int r = 0; r < 4; ++r)
                s4 += (ro + r < csel) ? fmaxf(ci[r], 0.f) : 0.f;
            s4 += __shfl_xor(s4, 16);       // g0+g1 -> A-sum, g2+g3 -> B-sum
            sv[nt] = s4;
        }
        if (g == 0) {
#pragma unroll
            for (int nt = 0; nt < 4; ++nt)
                sgrp[(long)(2 * ti) * 64 + nt * 16 + c] = sv[nt];
        }
        if (g == 2 && 2 * ti + 1 < G) {
#pragma unroll
            for (int nt = 0; nt < 4; ++nt)
                sgrp[(long)(2 * ti + 1) * 64 + nt * 16 + c] = sv[nt];
        }
    }
}

// ---------------- fused dense kernel: agg = S@W2 + deg*b2 ; h += relu([h,agg]@W3+b3)
__global__ __launch_bounds__(256) void k_node2(u16* __restrict__ hbx,
                                               const float* __restrict__ sgrp,
                                               const int* __restrict__ grp_ptr,
                                               const int* __restrict__ deg,
                                               const u16* __restrict__ Wsl,
                                               const float* __restrict__ b2,
                                               const float* __restrict__ b3,
                                               const u16* __restrict__ WslN,
                                               const float* __restrict__ b1N,
                                               float* __restrict__ accbT) {
    __shared__ u16 th[4][16 * 72];
    __shared__ u16 tl[4][16 * 72];
    int w = threadIdx.x >> 6, lane = threadIdx.x & 63;
    int tile = blockIdx.x * 4 + w;
    if (tile >= NTILE) return;
    int c = lane & 15, g = lane >> 4;
    int n0 = tile * 16, nr = n0 + c;
    u16* lh = th[w];
    u16* ll = tl[w];

    const bf16x8* W2H = (const bf16x8*)(Wsl + 8192);
    const bf16x8* W2L = (const bf16x8*)(Wsl + 28672);
    const bf16x8* W3H = (const bf16x8*)(Wsl + 12288);
    const bf16x8* W3L = (const bf16x8*)(Wsl + 32768);

    // build S fragments: sum node nr's groups, k-chunks 8g..8g+7 and 32+8g..+7
    int gp0 = grp_ptr[nr], gp1 = grp_ptr[nr + 1];
    f32x4 sA0 = {0, 0, 0, 0}, sA1 = {0, 0, 0, 0};
    f32x4 sB0 = {0, 0, 0, 0}, sB1 = {0, 0, 0, 0};
    for (int gi = gp0; gi < gp1; ++gi) {
        const f32x4* q = (const f32x4*)(sgrp + (long)gi * 64 + 8 * g);
        const f32x4* q2 = (const f32x4*)(sgrp + (long)gi * 64 + 32 + 8 * g);
        sA0 += q[0]; sA1 += q[1];
        sB0 += q2[0]; sB1 += q2[1];
    }
    bf16x8 S0h, S0l, S1h, S1l;
#pragma unroll
    for (int j = 0; j < 4; ++j) {
        u16 hi, lo;
        splt(sA0[j], hi, lo); S0h[j] = (short)hi; S0l[j] = (short)lo;
        splt(sA1[j], hi, lo); S0h[4 + j] = (short)hi; S0l[4 + j] = (short)lo;
        splt(sB0[j], hi, lo); S1h[j] = (short)hi; S1l[j] = (short)lo;
        splt(sB1[j], hi, lo); S1h[4 + j] = (short)hi; S1l[4 + j] = (short)lo;
    }

    const bf16x8* hp = (const bf16x8*)(hbx + (long)nr * 128);
    bf16x8 H0h = hp[g], H1h = hp[g + 4], H0l = hp[g + 8], H1l = hp[g + 12];

    float dg[4];
#pragma unroll
    for (int r = 0; r < 4; ++r) dg[r] = (float)deg[n0 + 4 * g + r];

    // GEMM2: agg (C-layout) -> LDS transpose planes
#pragma unroll
    for (int nt = 0; nt < 4; ++nt) {
        float b2c = b2[nt * 16 + c];
        f32x4 a = {dg[0] * b2c, dg[1] * b2c, dg[2] * b2c, dg[3] * b2c};
        a = MFMA16(S0h, W2H[nt * 64 + lane], a);
        a = MFMA16(S1h, W2H[(4 + nt) * 64 + lane], a);
        a = MFMA16(S0l, W2H[nt * 64 + lane], a);
        a = MFMA16(S1l, W2H[(4 + nt) * 64 + lane], a);
        a = MFMA16(S0h, W2L[nt * 64 + lane], a);
        a = MFMA16(S1h, W2L[(4 + nt) * 64 + lane], a);
#pragma unroll
        for (int r = 0; r < 4; ++r) {
            u16 hi, lo; splt(a[r], hi, lo);
            lh[(4 * g + r) * 72 + nt * 16 + c] = hi;
            ll[(4 * g + r) * 72 + nt * 16 + c] = lo;
        }
    }
    bf16x8 G0h = *(const bf16x8*)(lh + c * 72 + g * 8);
    bf16x8 G1h = *(const bf16x8*)(lh + c * 72 + 32 + g * 8);
    bf16x8 G0l = *(const bf16x8*)(ll + c * 72 + g * 8);
    bf16x8 G1l = *(const bf16x8*)(ll + c * 72 + 32 + g * 8);

    // GEMM3: u = [h, agg] @ W3 + b3
    f32x4 u4[4];
#pragma unroll
    for (int nt = 0; nt < 4; ++nt) {
        float bv = b3[nt * 16 + c];
        f32x4 u = {bv, bv, bv, bv};
        u = MFMA16(H0h, W3H[nt * 64 + lane], u);
        u = MFMA16(H1h, W3H[(4 + nt) * 64 + lane], u);
        u = MFMA16(G0h, W3H[(8 + nt) * 64 + lane], u);
        u = MFMA16(G1h, W3H[(12 + nt) * 64 + lane], u);
        u = MFMA16(H0l, W3H[nt * 64 + lane], u);
        u = MFMA16(H1l, W3H[(4 + nt) * 64 + lane], u);
        u = MFMA16(G0l, W3H[(8 + nt) * 64 + lane], u);
        u = MFMA16(G1l, W3H[(12 + nt) * 64 + lane], u);
        u = MFMA16(H0h, W3L[nt * 64 + lane], u);
        u = MFMA16(H1h, W3L[(4 + nt) * 64 + lane], u);
        u = MFMA16(G0h, W3L[(8 + nt) * 64 + lane], u);
        u = MFMA16(G1h, W3L[(12 + nt) * 64 + lane], u);
        u4[nt] = u;
    }

    // h update (reconstruct from pair) + pair write + stash for next dst-half
#pragma unroll
    for (int nt = 0; nt < 4; ++nt)
#pragma unroll
        for (int r = 0; r < 4; ++r) {
            long n = n0 + 4 * g + r;
            long ix = n * 128 + nt * 16 + c;
            float ho = b2f(hbx[ix]) + b2f(hbx[ix + 64]);
            float hn = ho + fmaxf(u4[nt][r], 0.f);
            u16 hi, lo; splt(hn, hi, lo);
            hbx[ix] = hi;
            hbx[ix + 64] = lo;
            lh[(4 * g + r) * 72 + nt * 16 + c] = hi;
            ll[(4 * g + r) * 72 + nt * 16 + c] = lo;
        }

    if (WslN) {
        bf16x8 N0h = *(const bf16x8*)(lh + c * 72 + g * 8);
        bf16x8 N1h = *(const bf16x8*)(lh + c * 72 + 32 + g * 8);
        bf16x8 N0l = *(const bf16x8*)(ll + c * 72 + g * 8);
        bf16x8 N1l = *(const bf16x8*)(ll + c * 72 + 32 + g * 8);
        const bf16x8* W1h = (const bf16x8*)WslN;
        const bf16x8* W1l = (const bf16x8*)(WslN + 20480);
        f32x4 acc4[4];
#pragma unroll
        for (int nt = 0; nt < 4; ++nt) {
            float bv = b1N[nt * 16 + c];
            f32x4 a = {bv, bv, bv, bv};
            a = MFMA16(N0h, W1h[(8 + nt) * 64 + lane], a);
            a = MFMA16(N1h, W1h[(12 + nt) * 64 + lane], a);
            a = MFMA16(N0l, W1h[(8 + nt) * 64 + lane], a);
            a = MFMA16(N1l, W1h[(12 + nt) * 64 + lane], a);
            a = MFMA16(N0h, W1l[(8 + nt) * 64 + lane], a);
            a = MFMA16(N1h, W1l[(12 + nt) * 64 + lane], a);
            acc4[nt] = a;
        }
#pragma unroll
        for (int r = 0; r < 4; ++r) {
            f32x4 wv = {acc4[0][r], acc4[1][r], acc4[2][r], acc4[3][r]};
            *(f32x4*)(accbT + (long)(n0 + 4 * g + r) * 64 + c * 4) = wv;
        }
    }
}

// ---------------- pooling ----------------
__global__ void k_granges(const int* __restrict__ batch, int* __restrict__ gpt) {
    int g = blockIdx.x * blockDim.x + threadIdx.x;
    if (g > 64) return;
    int lo = 0, hi = NN;
    while (lo < hi) {
        int mid = (lo + hi) >> 1;
        if (batch[mid] < g) lo = mid + 1; else hi = mid;
    }
    gpt[g] = lo;
}

__global__ __launch_bounds__(256) void k_sumrelu(const u16* __restrict__ hbx,
                                                 const int* __restrict__ gpt,
                                                 float* __restrict__ sumh) {
    int g = blockIdx.x >> 3, sp = blockIdx.x & 7;
    int lo = gpt[g], hi = gpt[g + 1];
    int n = hi - lo;
    int per = (n + 7) / 8;
    int s0 = lo + sp * per;
    int s1 = s0 + per; if (s1 > hi) s1 = hi;
    int lane = threadIdx.x & 63, wv = threadIdx.x >> 6;
    float acc = 0.f;
    for (int i = s0 + wv; i < s1; i += 4) {
        float v = b2f(hbx[(long)i * 128 + lane]) + b2f(hbx[(long)i * 128 + 64 + lane]);
        acc += fmaxf(v, 0.f);
    }
    if (acc != 0.f || wv == 0)
        atomicAdd(&sumh[g * 64 + lane], acc);
}

__global__ __launch_bounds__(256) void k_outgemm(const float* __restrict__ sumh,
                                                 const int* __restrict__ gpt,
                                                 const float* __restrict__ Wlin,
                                                 const float* __restrict__ blin,
                                                 float* __restrict__ out) {
    int idx = blockIdx.x * 256 + threadIdx.x;
    if (idx >= 64 * 32) return;
    int g = idx >> 5, o = idx & 31;
    int cnt = gpt[g + 1] - gpt[g];
    float acc = 0.f;
#pragma unroll 8
    for (int k = 0; k < 64; ++k)
        acc += sumh[g * 64 + k] * Wlin[k * 32 + o];
    out[idx] = (cnt > 0) ? (acc / (float)cnt + blin[o]) : 0.f;
}

extern "C" void kernel_launch(void* const* d_in, const int* in_sizes, int n_in,
                              void* d_out, int out_size, void* d_ws, size_t ws_size,
                              hipStream_t stream) {
    const float* pos    = (const float*)d_in[0];
    const int*   z      = (const int*)d_in[1];
    const int*   ei     = (const int*)d_in[2];
    const int*   batch  = (const int*)d_in[3];
    const float* emb    = (const float*)d_in[4];
    const float* t1_Win = (const float*)d_in[5];
    const float* t1_W1  = (const float*)d_in[6];
    const float* t1_b1  = (const float*)d_in[7];
    const float* t1_W2  = (const float*)d_in[8];
    const float* t1_b2  = (const float*)d_in[9];
    const float* t1_W3  = (const float*)d_in[10];
    const float* t1_b3  = (const float*)d_in[11];
    const float* t2_Win = (const float*)d_in[12];
    const float* t2_W1  = (const float*)d_in[13];
    const float* t2_b1  = (const float*)d_in[14];
    const float* t2_W2  = (const float*)d_in[15];
    const float* t2_b2  = (const float*)d_in[16];
    const float* t2_W3  = (const float*)d_in[17];
    const float* t2_b3  = (const float*)d_in[18];
    const float* Wlin   = (const float*)d_in[19];
    const float* blin   = (const float*)d_in[20];

    const int* srcI = ei;
    const int* dstI = ei + EE;

    char* ws = (char*)d_ws;
    size_t off = 0;
    auto alloc = [&](size_t bytes) -> void* {
        void* p = ws + off;
        off += (bytes + 255) / 256 * 256;
        return p;
    };
    float* accbT   = (float*)alloc((size_t)NN * 64 * 4);    // dst-half+b1 (transposed f32)
    u16*   hbx     = (u16*)alloc((size_t)NN * 128 * 2);     // h hi|lo pair (sole copy)
    float* sgrp    = (float*)alloc((size_t)GMAX * 64 * 4);  // per-group partial S (fp32)
    int*   deg     = (int*)alloc((size_t)NN * 4);
    int*   cursor  = (int*)alloc((size_t)NN * 4);
    int*   ngrpA   = (int*)alloc((size_t)NN * 4);
    int*   grp_ptr = (int*)alloc((size_t)(NN + 1) * 4);
    int*   gtab    = (int*)alloc((size_t)(GMAX + 2) * 4);
    int*   srcd2   = (int*)alloc((size_t)GMAX * 8 * 8);     // interleaved {src, d2bits}
    int*   gpt     = (int*)alloc(65 * 4);
    float* sumh    = (float*)alloc(64 * 64 * 4);
    int*   part    = (int*)alloc((SCB + 1) * 4);
    u16*   WsA     = (u16*)alloc((size_t)8 * 40960 * 2);
    u16*   WsB     = (u16*)alloc((size_t)16384 * 2);

    // prologue: degrees, group table (group-major interleaved), weights, ranges
    hipMemsetAsync(deg, 0, (size_t)NN * 4, stream);
    hipMemsetAsync(srcd2, 0, (size_t)GMAX * 8 * 8, stream);
    k_deg<<<(EE + 255) / 256, 256, 0, stream>>>(dstI, deg);
    k_ngrp<<<(NN + 255) / 256, 256, 0, stream>>>(deg, ngrpA);
    k_scanA<<<SCB, 1024, 0, stream>>>(ngrpA, part);
    k_scanB<<<1, 64, 0, stream>>>(part);
    k_scanC<<<SCB, 1024, 0, stream>>>(ngrpA, part, grp_ptr);
    k_curinit<<<(NN + 255) / 256, 256, 0, stream>>>(grp_ptr, cursor);
    k_scatter<<<(EE + 255) / 256, 256, 0, stream>>>(srcI, dstI, pos, cursor, srcd2);
    k_gtab<<<(NN + 255) / 256, 256, 0, stream>>>(deg, grp_ptr, gtab);
    k_swz<<<172032 / 256, 256, 0, stream>>>(t1_W1, t1_W2, t1_W3, t2_W1, t2_W2, t2_W3,
                                            t1_Win, t2_Win, WsA, WsB);
    k_granges<<<1, 128, 0, stream>>>(batch, gpt);

    // transformer 1 (proj fused with layer-0 dst-half)
    k_proj1<<<NTB, 256, 0, stream>>>(pos, z, emb, WsB, WsA, t1_b1, hbx, accbT);
    for (int l = 0; l < 4; ++l) {
        const u16* Wsl = WsA + (size_t)l * 40960;
        k_edges_mfma<<<EBLK, 256, 0, stream>>>(hbx, sgrp, srcd2, gtab, grp_ptr,
                                               Wsl, t1_W1 + (size_t)l * 129 * 64, accbT);
        const u16* WslN = (l < 3) ? (WsA + (size_t)(l + 1) * 40960) : nullptr;
        const float* b1N = (l < 3) ? (t1_b1 + (size_t)(l + 1) * 64) : nullptr;
        k_node2<<<NTB, 256, 0, stream>>>(hbx, sgrp, grp_ptr, deg, Wsl,
                                         t1_b2 + (size_t)l * 64, t1_b3 + (size_t)l * 64,
                                         WslN, b1N, accbT);
    }

    // transformer 2
    k_proj2<<<NTB, 256, 0, stream>>>(WsB + 8192, WsA + (size_t)4 * 40960, t2_b1,
                                     hbx, accbT);
    for (int l = 0; l < 4; ++l) {
        const u16* Wsl = WsA + (size_t)(4 + l) * 40960;
        k_edges_mfma<<<EBLK, 256, 0, stream>>>(hbx, sgrp, srcd2, gtab, grp_ptr,
                                               Wsl, t2_W1 + (size_t)l * 129 * 64, accbT);
        const u16* WslN = (l < 3) ? (WsA + (size_t)(5 + l) * 40960) : nullptr;
        const float* b1N = (l < 3) ? (t2_b1 + (size_t)(l + 1) * 64) : nullptr;
        k_node2<<<NTB, 256, 0, stream>>>(hbx, sgrp, grp_ptr, deg, Wsl,
                                         t2_b2 + (size_t)l * 64, t2_b3 + (size_t)l * 64,
                                         WslN, b1N, accbT);
    }

    // pooled mean
    hipMemsetAsync(sumh, 0, 64 * 64 * 4, stream);
    k_sumrelu<<<64 * 8, 256, 0, stream>>>(hbx, gpt, sumh);
    k_outgemm<<<8, 256, 0, stream>>>(sumh, gpt, Wlin, blin, (float*)d_out);
}

// Round 17
// 882.830 us; speedup vs baseline: 1.0501x; 1.0501x over previous
//
#include <hip/hip_runtime.h>
#include <hip/hip_bf16.h>

typedef unsigned short u16;
typedef unsigned int   u32;
typedef short bf16x8 __attribute__((ext_vector_type(8)));
typedef float f32x4  __attribute__((ext_vector_type(4)));
typedef int   i32x2  __attribute__((ext_vector_type(2)));

#define NN 100000
#define EE 800000
#define NTILE 6250            // NN/16
#define NTB   1563            // ceil(NTILE/4)
#define EBLK  1536            // persistent edge blocks = 6 blocks/CU x 256 CU
#define TOTW  (EBLK * 4)      // persistent edge waves
#define SCB   98              // scan blocks (98*1024 >= NN)
#define GMAX  (NN + EE / 8 + 2)

#define MFMA16(a,b,c) __builtin_amdgcn_mfma_f32_16x16x32_bf16(a,b,c,0,0,0)

__device__ __forceinline__ float b2f(u16 u) {
    u32 x = ((u32)u) << 16;
    return __uint_as_float(x);
}
__device__ __forceinline__ u16 f2b(float f) {
    __hip_bfloat16 h = __float2bfloat16(f);
    return *reinterpret_cast<u16*>(&h);
}
__device__ __forceinline__ void splt(float v, u16& hi, u16& lo) {
    hi = f2b(v);
    lo = f2b(v - b2f(hi));
}

// ---------------- degree + group-table build ----------------
__global__ __launch_bounds__(256) void k_deg(const int* __restrict__ dst,
                                             int* __restrict__ deg) {
    int e = blockIdx.x * 256 + threadIdx.x;
    if (e < EE) atomicAdd(&deg[dst[e]], 1);
}

__global__ __launch_bounds__(1024) void k_scanA(const int* __restrict__ deg,
                                                int* __restrict__ part) {
    __shared__ int s[1024];
    int i = blockIdx.x * 1024 + threadIdx.x;
    int v = (i < NN) ? deg[i] : 0;
    s[threadIdx.x] = v;
    __syncthreads();
    for (int off = 512; off > 0; off >>= 1) {
        if ((int)threadIdx.x < off) s[threadIdx.x] += s[threadIdx.x + off];
        __syncthreads();
    }
    if (threadIdx.x == 0) part[blockIdx.x] = s[0];
}

__global__ void k_scanB(int* __restrict__ part) {
    if (threadIdx.x == 0 && blockIdx.x == 0) {
        int run = 0;
        for (int b = 0; b < SCB; ++b) { int v = part[b]; part[b] = run; run += v; }
        part[SCB] = run;
    }
}

__global__ __launch_bounds__(1024) void k_scanC(const int* __restrict__ deg,
                                                const int* __restrict__ part,
                                                int* __restrict__ rowptr) {
    __shared__ int s[1024];
    int i = blockIdx.x * 1024 + threadIdx.x;
    int v = (i < NN) ? deg[i] : 0;
    s[threadIdx.x] = v;
    __syncthreads();
    for (int off = 1; off < 1024; off <<= 1) {
        int t = ((int)threadIdx.x >= off) ? s[threadIdx.x - off] : 0;
        __syncthreads();
        s[threadIdx.x] += t;
        __syncthreads();
    }
    int incl = s[threadIdx.x];
    if (i < NN) rowptr[i] = part[blockIdx.x] + incl - v;
    if (i == NN - 1) rowptr[NN] = part[SCB];
}

__global__ __launch_bounds__(256) void k_ngrp(const int* __restrict__ deg,
                                              int* __restrict__ ngrp) {
    int i = blockIdx.x * 256 + threadIdx.x;
    if (i < NN) ngrp[i] = (deg[i] + 7) >> 3;
}

__global__ __launch_bounds__(256) void k_curinit(const int* __restrict__ grp_ptr,
                                                 int* __restrict__ cursor) {
    int i = blockIdx.x * 256 + threadIdx.x;
    if (i < NN) cursor[i] = grp_ptr[i] * 8;
}

// scatter edges into group-major interleaved slots: one 8B store per edge
__global__ __launch_bounds__(256) void k_scatter(const int* __restrict__ src,
                                                 const int* __restrict__ dst,
                                                 const float* __restrict__ pos,
                                                 int* __restrict__ cursor,
                                                 int* __restrict__ srcd2) {
    int e = blockIdx.x * 256 + threadIdx.x;
    if (e >= EE) return;
    int d = dst[e], s = src[e];
    int p = atomicAdd(&cursor[d], 1);
    float dx = pos[s * 3 + 0] - pos[d * 3 + 0];
    float dy = pos[s * 3 + 1] - pos[d * 3 + 1];
    float dz = pos[s * 3 + 2] - pos[d * 3 + 2];
    float d2 = dx * dx + dy * dy + dz * dz;
    i32x2 st = {s, __float_as_int(d2)};
    *(i32x2*)(srcd2 + 2L * p) = st;
}

// coalesced de-interleave: srcd2 -> srcg + d2g
__global__ __launch_bounds__(256) void k_split(const int* __restrict__ srcd2,
                                               int* __restrict__ srcg,
                                               float* __restrict__ d2g) {
    long i = (long)blockIdx.x * 256 + threadIdx.x;
    if (i >= (long)GMAX * 8) return;
    i32x2 v = *(const i32x2*)(srcd2 + 2 * i);
    srcg[i] = v[0];
    d2g[i] = __int_as_float(v[1]);
}

// packed group table: gtab[g] = (node<<4) | cnt  (cnt in 1..8); pad entry at [G]
__global__ __launch_bounds__(256) void k_gtab(const int* __restrict__ deg,
                                              const int* __restrict__ grp_ptr,
                                              int* __restrict__ gtab) {
    int n = blockIdx.x * 256 + threadIdx.x;
    if (n >= NN) return;
    if (n == 0) gtab[grp_ptr[NN]] = 0;
    int d = deg[n];
    int ng = (d + 7) >> 3;
    int base = grp_ptr[n];
    for (int k = 0; k < ng; ++k) {
        int cc = d - 8 * k; if (cc > 8) cc = 8;
        gtab[base + k] = (n << 4) | cc;
    }
}

// ---------------- weight swizzle (fp32 -> bf16 hi/lo B-frags) ----------------
__global__ __launch_bounds__(256) void k_swz(const float* t1W1, const float* t1W2, const float* t1W3,
                                             const float* t2W1, const float* t2W2, const float* t2W3,
                                             const float* t1Win, const float* t2Win,
                                             u16* __restrict__ WsA, u16* __restrict__ WsB) {
    int gid = blockIdx.x * 256 + threadIdx.x;   // 172032 exactly
    if (gid < 163840) {
        int L = gid / 20480;
        int r = gid % 20480;
        const float* W1 = (L < 4 ? t1W1 : t2W1) + (size_t)(L & 3) * 129 * 64;
        const float* W2 = (L < 4 ? t1W2 : t2W2) + (size_t)(L & 3) * 64 * 64;
        const float* W3 = (L < 4 ? t1W3 : t2W3) + (size_t)(L & 3) * 128 * 64;
        float w;
        int rr, f, e, lane, j, row, col;
        if (r < 8192) { rr = r; f = rr >> 9; e = rr & 511; lane = e >> 3; j = e & 7;
            row = (f >> 2) * 32 + (lane >> 4) * 8 + j; col = (f & 3) * 16 + (lane & 15);
            w = W1[row * 64 + col];
        } else if (r < 12288) { rr = r - 8192; f = rr >> 9; e = rr & 511; lane = e >> 3; j = e & 7;
            row = (f >> 2) * 32 + (lane >> 4) * 8 + j; col = (f & 3) * 16 + (lane & 15);
            w = W2[row * 64 + col];
        } else { rr = r - 12288; f = rr >> 9; e = rr & 511; lane = e >> 3; j = e & 7;
            row = (f >> 2) * 32 + (lane >> 4) * 8 + j; col = (f & 3) * 16 + (lane & 15);
            w = W3[row * 64 + col];
        }
        u16 hi, lo; splt(w, hi, lo);
        WsA[(size_t)L * 40960 + r] = hi;
        WsA[(size_t)L * 40960 + 20480 + r] = lo;
    } else {
        int t = gid - 163840;
        int sel = (t < 4096) ? 0 : 1;
        int rr = t & 4095;
        const float* Win = sel ? t2Win : t1Win;
        int f = rr >> 9, e = rr & 511, lane = e >> 3, j = e & 7;
        int row = (f >> 2) * 32 + (lane >> 4) * 8 + j;
        int col = (f & 3) * 16 + (lane & 15);
        float w = Win[row * 64 + col];
        u16 hi, lo; splt(w, hi, lo);
        WsB[sel * 8192 + rr] = hi;
        WsB[sel * 8192 + 4096 + rr] = lo;
    }
}

// ---------------- t1 proj fused with embed + layer-0 dst-half ----------------
__global__ __launch_bounds__(256) void k_proj1(const float* __restrict__ pos,
                                               const int* __restrict__ z,
                                               const float* __restrict__ emb,
                                               const u16* __restrict__ WinS,
                                               const u16* __restrict__ Wsl0,
                                               const float* __restrict__ b1,
                                               u16* __restrict__ hbx,
                                               float* __restrict__ accbT) {
    __shared__ u16 th[4][16 * 72];
    __shared__ u16 tl[4][16 * 72];
    int w = threadIdx.x >> 6;
    int tile = blockIdx.x * 4 + w;
    if (tile >= NTILE) return;
    int lane = threadIdx.x & 63, c = lane & 15, g = lane >> 4;
    int n0 = tile * 16, nr = n0 + c;
    u16* lh = th[w];
    u16* ll = tl[w];
    int zr = z[nr];
    const float* er = emb + (long)zr * 61 - 3;
    bf16x8 A0h, A0l, A1h, A1l;
#pragma unroll
    for (int j = 0; j < 8; ++j) {
        int f = 8 * g + j;
        float v1 = (f < 3) ? pos[nr * 3 + (f < 3 ? f : 0)] : er[f];
        float v2 = er[32 + 8 * g + j];
        u16 hi, lo;
        splt(v1, hi, lo); A0h[j] = (short)hi; A0l[j] = (short)lo;
        splt(v2, hi, lo); A1h[j] = (short)hi; A1l[j] = (short)lo;
    }
    const bf16x8* Wh = (const bf16x8*)WinS;
    const bf16x8* Wl = (const bf16x8*)(WinS + 4096);
#pragma unroll
    for (int nt = 0; nt < 4; ++nt) {
        f32x4 acc = {0.f, 0.f, 0.f, 0.f};
        acc = MFMA16(A0h, Wh[nt * 64 + lane], acc);
        acc = MFMA16(A1h, Wh[(4 + nt) * 64 + lane], acc);
        acc = MFMA16(A0l, Wh[nt * 64 + lane], acc);
        acc = MFMA16(A1l, Wh[(4 + nt) * 64 + lane], acc);
        acc = MFMA16(A0h, Wl[nt * 64 + lane], acc);
        acc = MFMA16(A1h, Wl[(4 + nt) * 64 + lane], acc);
#pragma unroll
        for (int r = 0; r < 4; ++r) {
            long n = n0 + 4 * g + r;
            u16 hi, lo; splt(acc[r], hi, lo);
            hbx[n * 128 + nt * 16 + c] = hi;
            hbx[n * 128 + 64 + nt * 16 + c] = lo;
            lh[(4 * g + r) * 72 + nt * 16 + c] = hi;
            ll[(4 * g + r) * 72 + nt * 16 + c] = lo;
        }
    }
    // layer-0 dst-half from LDS transpose (wave-private plane, no barrier)
    bf16x8 N0h = *(const bf16x8*)(lh + c * 72 + g * 8);
    bf16x8 N1h = *(const bf16x8*)(lh + c * 72 + 32 + g * 8);
    bf16x8 N0l = *(const bf16x8*)(ll + c * 72 + g * 8);
    bf16x8 N1l = *(const bf16x8*)(ll + c * 72 + 32 + g * 8);
    const bf16x8* W1h = (const bf16x8*)Wsl0;
    const bf16x8* W1l = (const bf16x8*)(Wsl0 + 20480);
    f32x4 acc4[4];
#pragma unroll
    for (int nt = 0; nt < 4; ++nt) {
        float bv = b1[nt * 16 + c];
        f32x4 a = {bv, bv, bv, bv};
        a = MFMA16(N0h, W1h[(8 + nt) * 64 + lane], a);
        a = MFMA16(N1h, W1h[(12 + nt) * 64 + lane], a);
        a = MFMA16(N0l, W1h[(8 + nt) * 64 + lane], a);
        a = MFMA16(N1l, W1h[(12 + nt) * 64 + lane], a);
        a = MFMA16(N0h, W1l[(8 + nt) * 64 + lane], a);
        a = MFMA16(N1h, W1l[(12 + nt) * 64 + lane], a);
        acc4[nt] = a;
    }
#pragma unroll
    for (int r = 0; r < 4; ++r) {
        f32x4 wv = {acc4[0][r], acc4[1][r], acc4[2][r], acc4[3][r]};
        *(f32x4*)(accbT + (long)(n0 + 4 * g + r) * 64 + c * 4) = wv;
    }
}

// ---------------- t2 proj fused with relu + layer-0 dst-half (in-place hbx) --
__global__ __launch_bounds__(256) void k_proj2(const u16* __restrict__ WinS,
                                               const u16* __restrict__ Wsl0,
                                               const float* __restrict__ b1,
                                               u16* __restrict__ hbx,
                                               float* __restrict__ accbT) {
    __shared__ u16 th[4][16 * 72];
    __shared__ u16 tl[4][16 * 72];
    int w = threadIdx.x >> 6;
    int tile = blockIdx.x * 4 + w;
    if (tile >= NTILE) return;
    int lane = threadIdx.x & 63, c = lane & 15, g = lane >> 4;
    int n0 = tile * 16, nr = n0 + c;
    u16* lh = th[w];
    u16* ll = tl[w];
    const bf16x8* p = (const bf16x8*)(hbx + (long)nr * 128);
    bf16x8 h0 = p[g], h1 = p[g + 4], l0 = p[g + 8], l1 = p[g + 12];
    bf16x8 A0h, A0l, A1h, A1l;
#pragma unroll
    for (int j = 0; j < 8; ++j) {
        float v1 = fmaxf(b2f((u16)h0[j]) + b2f((u16)l0[j]), 0.f);
        float v2 = fmaxf(b2f((u16)h1[j]) + b2f((u16)l1[j]), 0.f);
        u16 hi, lo;
        splt(v1, hi, lo); A0h[j] = (short)hi; A0l[j] = (short)lo;
        splt(v2, hi, lo); A1h[j] = (short)hi; A1l[j] = (short)lo;
    }
    const bf16x8* Wh = (const bf16x8*)WinS;
    const bf16x8* Wl = (const bf16x8*)(WinS + 4096);
#pragma unroll
    for (int nt = 0; nt < 4; ++nt) {
        f32x4 acc = {0.f, 0.f, 0.f, 0.f};
        acc = MFMA16(A0h, Wh[nt * 64 + lane], acc);
        acc = MFMA16(A1h, Wh[(4 + nt) * 64 + lane], acc);
        acc = MFMA16(A0l, Wh[nt * 64 + lane], acc);
        acc = MFMA16(A1l, Wh[(4 + nt) * 64 + lane], acc);
        acc = MFMA16(A0h, Wl[nt * 64 + lane], acc);
        acc = MFMA16(A1h, Wl[(4 + nt) * 64 + lane], acc);
#pragma unroll
        for (int r = 0; r < 4; ++r) {
            long n = n0 + 4 * g + r;
            u16 hi, lo; splt(acc[r], hi, lo);
            hbx[n * 128 + nt * 16 + c] = hi;
            hbx[n * 128 + 64 + nt * 16 + c] = lo;
            lh[(4 * g + r) * 72 + nt * 16 + c] = hi;
            ll[(4 * g + r) * 72 + nt * 16 + c] = lo;
        }
    }
    bf16x8 N0h = *(const bf16x8*)(lh + c * 72 + g * 8);
    bf16x8 N1h = *(const bf16x8*)(lh + c * 72 + 32 + g * 8);
    bf16x8 N0l = *(const bf16x8*)(ll + c * 72 + g * 8);
    bf16x8 N1l = *(const bf16x8*)(ll + c * 72 + 32 + g * 8);
    const bf16x8* W1h = (const bf16x8*)Wsl0;
    const bf16x8* W1l = (const bf16x8*)(Wsl0 + 20480);
    f32x4 acc4[4];
#pragma unroll
    for (int nt = 0; nt < 4; ++nt) {
        float bv = b1[nt * 16 + c];
        f32x4 a = {bv, bv, bv, bv};
        a = MFMA16(N0h, W1h[(8 + nt) * 64 + lane], a);
        a = MFMA16(N1h, W1h[(12 + nt) * 64 + lane], a);
        a = MFMA16(N0l, W1h[(8 + nt) * 64 + lane], a);
        a = MFMA16(N1l, W1h[(12 + nt) * 64 + lane], a);
        a = MFMA16(N0h, W1l[(8 + nt) * 64 + lane], a);
        a = MFMA16(N1h, W1l[(12 + nt) * 64 + lane], a);
        acc4[nt] = a;
    }
#pragma unroll
    for (int r = 0; r < 4; ++r) {
        f32x4 wv = {acc4[0][r], acc4[1][r], acc4[2][r], acc4[3][r]};
        *(f32x4*)(accbT + (long)(n0 + 4 * g + r) * 64 + c * 4) = wv;
    }
}

// ---------------- edge kernel: two 8-edge groups per MFMA tile ---------------
// group-major srcg/d2g + packed gtab; partial sums -> sgrp[G,64] fp32
__global__ __launch_bounds__(256) void k_edges_mfma(const u16* __restrict__ hbx,
                                                    float* __restrict__ sgrp,
                                                    const float* __restrict__ d2g,
                                                    const int* __restrict__ srcg,
                                                    const int* __restrict__ gtab,
                                                    const int* __restrict__ grp_ptr,
                                                    const u16* __restrict__ Wsl,
                                                    const float* __restrict__ W1f,
                                                    const float* __restrict__ accbT) {
    int lane = threadIdx.x & 63;
    int wid = blockIdx.x * 4 + (threadIdx.x >> 6);
    int c = lane & 15, g = lane >> 4;
    const bf16x8* W1H = (const bf16x8*)Wsl;
    const bf16x8* W1L = (const bf16x8*)(Wsl + 20480);
    bf16x8 w1h[2][4], w1l[2][4];
#pragma unroll
    for (int ks = 0; ks < 2; ++ks)
#pragma unroll
        for (int nt = 0; nt < 4; ++nt) {
            w1h[ks][nt] = W1H[(ks * 4 + nt) * 64 + lane];
            w1l[ks][nt] = W1L[(ks * 4 + nt) * 64 + lane];
        }
    float wdc[4];
#pragma unroll
    for (int nt = 0; nt < 4; ++nt) wdc[nt] = W1f[128 * 64 + nt * 16 + c];

    int G = grp_ptr[NN];
    int T = (G + 1) >> 1;
    int ro = 4 * (g & 1);

    for (int ti = wid; ti < T; ti += TOTW) {
        i32x2 pk = *(const i32x2*)(gtab + 2 * ti);
        int psel = (g < 2) ? pk[0] : pk[1];
        int nsel = psel >> 4;
        int csel = psel & 15;

        f32x4 bse = *(const f32x4*)(accbT + (long)nsel * 64 + c * 4);
        int s = srcg[(long)ti * 16 + c];
        const bf16x8* sp = (const bf16x8*)(hbx + (long)s * 128);
        bf16x8 A0h = sp[g], A1h = sp[g + 4], A0l = sp[g + 8], A1l = sp[g + 12];
        f32x4 dq = *(const f32x4*)(d2g + (long)ti * 16 + 8 * (g >> 1) + ro);

        float sv[4];
#pragma unroll
        for (int nt = 0; nt < 4; ++nt) {
            f32x4 ci;
#pragma unroll
            for (int r = 0; r < 4; ++r) ci[r] = bse[nt] + dq[r] * wdc[nt];
            ci = MFMA16(A0h, w1h[0][nt], ci);
            ci = MFMA16(A1h, w1h[1][nt], ci);
            ci = MFMA16(A0l, w1h[0][nt], ci);
            ci = MFMA16(A1l, w1h[1][nt], ci);
            ci = MFMA16(A0h, w1l[0][nt], ci);
            ci = MFMA16(A1h, w1l[1][nt], ci);
            float s4 = 0.f;
#pragma unroll
            for (int r = 0; r < 4; ++r)
                s4 += (ro + r < csel) ? fmaxf(ci[r], 0.f) : 0.f;
            s4 += __shfl_xor(s4, 16);       // g0+g1 -> A-sum, g2+g3 -> B-sum
            sv[nt] = s4;
        }
        if (g == 0) {
#pragma unroll
            for (int nt = 0; nt < 4; ++nt)
                sgrp[(long)(2 * ti) * 64 + nt * 16 + c] = sv[nt];
        }
        if (g == 2 && 2 * ti + 1 < G) {
#pragma unroll
            for (int nt = 0; nt < 4; ++nt)
                sgrp[(long)(2 * ti + 1) * 64 + nt * 16 + c] = sv[nt];
        }
    }
}

// ---------------- fused dense kernel: agg = S@W2 + deg*b2 ; h += relu([h,agg]@W3+b3)
__global__ __launch_bounds__(256) void k_node2(u16* __restrict__ hbx,
                                               const float* __restrict__ sgrp,
                                               const int* __restrict__ grp_ptr,
                                               const int* __restrict__ deg,
                                               const u16* __restrict__ Wsl,
                                               const float* __restrict__ b2,
                                               const float* __restrict__ b3,
                                               const u16* __restrict__ WslN,
                                               const float* __restrict__ b1N,
                                               float* __restrict__ accbT) {
    __shared__ u16 th[4][16 * 72];
    __shared__ u16 tl[4][16 * 72];
    int w = threadIdx.x >> 6, lane = threadIdx.x & 63;
    int tile = blockIdx.x * 4 + w;
    if (tile >= NTILE) return;
    int c = lane & 15, g = lane >> 4;
    int n0 = tile * 16, nr = n0 + c;
    u16* lh = th[w];
    u16* ll = tl[w];

    const bf16x8* W2H = (const bf16x8*)(Wsl + 8192);
    const bf16x8* W2L = (const bf16x8*)(Wsl + 28672);
    const bf16x8* W3H = (const bf16x8*)(Wsl + 12288);
    const bf16x8* W3L = (const bf16x8*)(Wsl + 32768);

    // build S fragments: sum node nr's groups, k-chunks 8g..8g+7 and 32+8g..+7
    int gp0 = grp_ptr[nr], gp1 = grp_ptr[nr + 1];
    f32x4 sA0 = {0, 0, 0, 0}, sA1 = {0, 0, 0, 0};
    f32x4 sB0 = {0, 0, 0, 0}, sB1 = {0, 0, 0, 0};
    for (int gi = gp0; gi < gp1; ++gi) {
        const f32x4* q = (const f32x4*)(sgrp + (long)gi * 64 + 8 * g);
        const f32x4* q2 = (const f32x4*)(sgrp + (long)gi * 64 + 32 + 8 * g);
        sA0 += q[0]; sA1 += q[1];
        sB0 += q2[0]; sB1 += q2[1];
    }
    bf16x8 S0h, S0l, S1h, S1l;
#pragma unroll
    for (int j = 0; j < 4; ++j) {
        u16 hi, lo;
        splt(sA0[j], hi, lo); S0h[j] = (short)hi; S0l[j] = (short)lo;
        splt(sA1[j], hi, lo); S0h[4 + j] = (short)hi; S0l[4 + j] = (short)lo;
        splt(sB0[j], hi, lo); S1h[j] = (short)hi; S1l[j] = (short)lo;
        splt(sB1[j], hi, lo); S1h[4 + j] = (short)hi; S1l[4 + j] = (short)lo;
    }

    const bf16x8* hp = (const bf16x8*)(hbx + (long)nr * 128);
    bf16x8 H0h = hp[g], H1h = hp[g + 4], H0l = hp[g + 8], H1l = hp[g + 12];

    float dg[4];
#pragma unroll
    for (int r = 0; r < 4; ++r) dg[r] = (float)deg[n0 + 4 * g + r];

    // GEMM2: agg (C-layout) -> LDS transpose planes
#pragma unroll
    for (int nt = 0; nt < 4; ++nt) {
        float b2c = b2[nt * 16 + c];
        f32x4 a = {dg[0] * b2c, dg[1] * b2c, dg[2] * b2c, dg[3] * b2c};
        a = MFMA16(S0h, W2H[nt * 64 + lane], a);
        a = MFMA16(S1h, W2H[(4 + nt) * 64 + lane], a);
        a = MFMA16(S0l, W2H[nt * 64 + lane], a);
        a = MFMA16(S1l, W2H[(4 + nt) * 64 + lane], a);
        a = MFMA16(S0h, W2L[nt * 64 + lane], a);
        a = MFMA16(S1h, W2L[(4 + nt) * 64 + lane], a);
#pragma unroll
        for (int r = 0; r < 4; ++r) {
            u16 hi, lo; splt(a[r], hi, lo);
            lh[(4 * g + r) * 72 + nt * 16 + c] = hi;
            ll[(4 * g + r) * 72 + nt * 16 + c] = lo;
        }
    }
    bf16x8 G0h = *(const bf16x8*)(lh + c * 72 + g * 8);
    bf16x8 G1h = *(const bf16x8*)(lh + c * 72 + 32 + g * 8);
    bf16x8 G0l = *(const bf16x8*)(ll + c * 72 + g * 8);
    bf16x8 G1l = *(const bf16x8*)(ll + c * 72 + 32 + g * 8);

    // GEMM3: u = [h, agg] @ W3 + b3
    f32x4 u4[4];
#pragma unroll
    for (int nt = 0; nt < 4; ++nt) {
        float bv = b3[nt * 16 + c];
        f32x4 u = {bv, bv, bv, bv};
        u = MFMA16(H0h, W3H[nt * 64 + lane], u);
        u = MFMA16(H1h, W3H[(4 + nt) * 64 + lane], u);
        u = MFMA16(G0h, W3H[(8 + nt) * 64 + lane], u);
        u = MFMA16(G1h, W3H[(12 + nt) * 64 + lane], u);
        u = MFMA16(H0l, W3H[nt * 64 + lane], u);
        u = MFMA16(H1l, W3H[(4 + nt) * 64 + lane], u);
        u = MFMA16(G0l, W3H[(8 + nt) * 64 + lane], u);
        u = MFMA16(G1l, W3H[(12 + nt) * 64 + lane], u);
        u = MFMA16(H0h, W3L[nt * 64 + lane], u);
        u = MFMA16(H1h, W3L[(4 + nt) * 64 + lane], u);
        u = MFMA16(G0h, W3L[(8 + nt) * 64 + lane], u);
        u = MFMA16(G1h, W3L[(12 + nt) * 64 + lane], u);
        u4[nt] = u;
    }

    // h update (reconstruct from pair) + pair write + stash for next dst-half
#pragma unroll
    for (int nt = 0; nt < 4; ++nt)
#pragma unroll
        for (int r = 0; r < 4; ++r) {
            long n = n0 + 4 * g + r;
            long ix = n * 128 + nt * 16 + c;
            float ho = b2f(hbx[ix]) + b2f(hbx[ix + 64]);
            float hn = ho + fmaxf(u4[nt][r], 0.f);
            u16 hi, lo; splt(hn, hi, lo);
            hbx[ix] = hi;
            hbx[ix + 64] = lo;
            lh[(4 * g + r) * 72 + nt * 16 + c] = hi;
            ll[(4 * g + r) * 72 + nt * 16 + c] = lo;
        }

    if (WslN) {
        bf16x8 N0h = *(const bf16x8*)(lh + c * 72 + g * 8);
        bf16x8 N1h = *(const bf16x8*)(lh + c * 72 + 32 + g * 8);
        bf16x8 N0l = *(const bf16x8*)(ll + c * 72 + g * 8);
        bf16x8 N1l = *(const bf16x8*)(ll + c * 72 + 32 + g * 8);
        const bf16x8* W1h = (const bf16x8*)WslN;
        const bf16x8* W1l = (const bf16x8*)(WslN + 20480);
        f32x4 acc4[4];
#pragma unroll
        for (int nt = 0; nt < 4; ++nt) {
            float bv = b1N[nt * 16 + c];
            f32x4 a = {bv, bv, bv, bv};
            a = MFMA16(N0h, W1h[(8 + nt) * 64 + lane], a);
            a = MFMA16(N1h, W1h[(12 + nt) * 64 + lane], a);
            a = MFMA16(N0l, W1h[(8 + nt) * 64 + lane], a);
            a = MFMA16(N1l, W1h[(12 + nt) * 64 + lane], a);
            a = MFMA16(N0h, W1l[(8 + nt) * 64 + lane], a);
            a = MFMA16(N1h, W1l[(12 + nt) * 64 + lane], a);
            acc4[nt] = a;
        }
#pragma unroll
        for (int r = 0; r < 4; ++r) {
            f32x4 wv = {acc4[0][r], acc4[1][r], acc4[2][r], acc4[3][r]};
            *(f32x4*)(accbT + (long)(n0 + 4 * g + r) * 64 + c * 4) = wv;
        }
    }
}

// ---------------- pooling ----------------
__global__ void k_granges(const int* __restrict__ batch, int* __restrict__ gpt) {
    int g = blockIdx.x * blockDim.x + threadIdx.x;
    if (g > 64) return;
    int lo = 0, hi = NN;
    while (lo < hi) {
        int mid = (lo + hi) >> 1;
        if (batch[mid] < g) lo = mid + 1; else hi = mid;
    }
    gpt[g] = lo;
}

__global__ __launch_bounds__(256) void k_sumrelu(const u16* __restrict__ hbx,
                                                 const int* __restrict__ gpt,
                                                 float* __restrict__ sumh) {
    int g = blockIdx.x >> 3, sp = blockIdx.x & 7;
    int lo = gpt[g], hi = gpt[g + 1];
    int n = hi - lo;
    int per = (n + 7) / 8;
    int s0 = lo + sp * per;
    int s1 = s0 + per; if (s1 > hi) s1 = hi;
    int lane = threadIdx.x & 63, wv = threadIdx.x >> 6;
    float acc = 0.f;
    for (int i = s0 + wv; i < s1; i += 4) {
        float v = b2f(hbx[(long)i * 128 + lane]) + b2f(hbx[(long)i * 128 + 64 + lane]);
        acc += fmaxf(v, 0.f);
    }
    if (acc != 0.f || wv == 0)
        atomicAdd(&sumh[g * 64 + lane], acc);
}

__global__ __launch_bounds__(256) void k_outgemm(const float* __restrict__ sumh,
                                                 const int* __restrict__ gpt,
                                                 const float* __restrict__ Wlin,
                                                 const float* __restrict__ blin,
                                                 float* __restrict__ out) {
    int idx = blockIdx.x * 256 + threadIdx.x;
    if (idx >= 64 * 32) return;
    int g = idx >> 5, o = idx & 31;
    int cnt = gpt[g + 1] - gpt[g];
    float acc = 0.f;
#pragma unroll 8
    for (int k = 0; k < 64; ++k)
        acc += sumh[g * 64 + k] * Wlin[k * 32 + o];
    out[idx] = (cnt > 0) ? (acc / (float)cnt + blin[o]) : 0.f;
}

extern "C" void kernel_launch(void* const* d_in, const int* in_sizes, int n_in,
                              void* d_out, int out_size, void* d_ws, size_t ws_size,
                              hipStream_t stream) {
    const float* pos    = (const float*)d_in[0];
    const int*   z      = (const int*)d_in[1];
    const int*   ei     = (const int*)d_in[2];
    const int*   batch  = (const int*)d_in[3];
    const float* emb    = (const float*)d_in[4];
    const float* t1_Win = (const float*)d_in[5];
    const float* t1_W1  = (const float*)d_in[6];
    const float* t1_b1  = (const float*)d_in[7];
    const float* t1_W2  = (const float*)d_in[8];
    const float* t1_b2  = (const float*)d_in[9];
    const float* t1_W3  = (const float*)d_in[10];
    const float* t1_b3  = (const float*)d_in[11];
    const float* t2_Win = (const float*)d_in[12];
    const float* t2_W1  = (const float*)d_in[13];
    const float* t2_b1  = (const float*)d_in[14];
    const float* t2_W2  = (const float*)d_in[15];
    const float* t2_b2  = (const float*)d_in[16];
    const float* t2_W3  = (const float*)d_in[17];
    const float* t2_b3  = (const float*)d_in[18];
    const float* Wlin   = (const float*)d_in[19];
    const float* blin   = (const float*)d_in[20];

    const int* srcI = ei;
    const int* dstI = ei + EE;

    char* ws = (char*)d_ws;
    size_t off = 0;
    auto alloc = [&](size_t bytes) -> void* {
        void* p = ws + off;
        off += (bytes + 255) / 256 * 256;
        return p;
    };
    float* accbT   = (float*)alloc((size_t)NN * 64 * 4);    // dst-half+b1 (transposed f32)
    u16*   hbx     = (u16*)alloc((size_t)NN * 128 * 2);     // h hi|lo pair (sole copy)
    float* sgrp    = (float*)alloc((size_t)GMAX * 64 * 4);  // per-group partial S (fp32)
    int*   deg     = (int*)alloc((size_t)NN * 4);
    int*   cursor  = (int*)alloc((size_t)NN * 4);
    int*   ngrpA   = (int*)alloc((size_t)NN * 4);
    int*   grp_ptr = (int*)alloc((size_t)(NN + 1) * 4);
    int*   gtab    = (int*)alloc((size_t)(GMAX + 2) * 4);
    int*   srcd2   = (int*)alloc((size_t)GMAX * 8 * 8);     // interleaved {src, d2bits}
    int*   srcg    = (int*)alloc((size_t)GMAX * 8 * 4);
    float* d2g     = (float*)alloc((size_t)GMAX * 8 * 4);
    int*   gpt     = (int*)alloc(65 * 4);
    float* sumh    = (float*)alloc(64 * 64 * 4);
    int*   part    = (int*)alloc((SCB + 1) * 4);
    u16*   WsA     = (u16*)alloc((size_t)8 * 40960 * 2);
    u16*   WsB     = (u16*)alloc((size_t)16384 * 2);

    // prologue: degrees, group table, weights, graph ranges
    hipMemsetAsync(deg, 0, (size_t)NN * 4, stream);
    hipMemsetAsync(srcd2, 0, (size_t)GMAX * 8 * 8, stream);
    k_deg<<<(EE + 255) / 256, 256, 0, stream>>>(dstI, deg);
    k_ngrp<<<(NN + 255) / 256, 256, 0, stream>>>(deg, ngrpA);
    k_scanA<<<SCB, 1024, 0, stream>>>(ngrpA, part);
    k_scanB<<<1, 64, 0, stream>>>(part);
    k_scanC<<<SCB, 1024, 0, stream>>>(ngrpA, part, grp_ptr);
    k_curinit<<<(NN + 255) / 256, 256, 0, stream>>>(grp_ptr, cursor);
    k_scatter<<<(EE + 255) / 256, 256, 0, stream>>>(srcI, dstI, pos, cursor, srcd2);
    k_split<<<((size_t)GMAX * 8 + 255) / 256, 256, 0, stream>>>(srcd2, srcg, d2g);
    k_gtab<<<(NN + 255) / 256, 256, 0, stream>>>(deg, grp_ptr, gtab);
    k_swz<<<172032 / 256, 256, 0, stream>>>(t1_W1, t1_W2, t1_W3, t2_W1, t2_W2, t2_W3,
                                            t1_Win, t2_Win, WsA, WsB);
    k_granges<<<1, 128, 0, stream>>>(batch, gpt);

    // transformer 1 (proj fused with layer-0 dst-half)
    k_proj1<<<NTB, 256, 0, stream>>>(pos, z, emb, WsB, WsA, t1_b1, hbx, accbT);
    for (int l = 0; l < 4; ++l) {
        const u16* Wsl = WsA + (size_t)l * 40960;
        k_edges_mfma<<<EBLK, 256, 0, stream>>>(hbx, sgrp, d2g, srcg, gtab, grp_ptr,
                                               Wsl, t1_W1 + (size_t)l * 129 * 64, accbT);
        const u16* WslN = (l < 3) ? (WsA + (size_t)(l + 1) * 40960) : nullptr;
        const float* b1N = (l < 3) ? (t1_b1 + (size_t)(l + 1) * 64) : nullptr;
        k_node2<<<NTB, 256, 0, stream>>>(hbx, sgrp, grp_ptr, deg, Wsl,
                                         t1_b2 + (size_t)l * 64, t1_b3 + (size_t)l * 64,
                                         WslN, b1N, accbT);
    }

    // transformer 2
    k_proj2<<<NTB, 256, 0, stream>>>(WsB + 8192, WsA + (size_t)4 * 40960, t2_b1,
                                     hbx, accbT);
    for (int l = 0; l < 4; ++l) {
        const u16* Wsl = WsA + (size_t)(4 + l) * 40960;
        k_edges_mfma<<<EBLK, 256, 0, stream>>>(hbx, sgrp, d2g, srcg, gtab, grp_ptr,
                                               Wsl, t2_W1 + (size_t)l * 129 * 64, accbT);
        const u16* WslN = (l < 3) ? (WsA + (size_t)(5 + l) * 40960) : nullptr;
        const float* b1N = (l < 3) ? (t2_b1 + (size_t)(l + 1) * 64) : nullptr;
        k_node2<<<NTB, 256, 0, stream>>>(hbx, sgrp, grp_ptr, deg, Wsl,
                                         t2_b2 + (size_t)l * 64, t2_b3 + (size_t)l * 64,
                                         WslN, b1N, accbT);
    }

    // pooled mean
    hipMemsetAsync(sumh, 0, 64 * 64 * 4, stream);
    k_sumrelu<<<64 * 8, 256, 0, stream>>>(hbx, gpt, sumh);
    k_outgemm<<<8, 256, 0, stream>>>(sumh, gpt, Wlin, blin, (float*)d_out);
}